// Round 6
// baseline (388.228 us; speedup 1.0000x reference)
//
#include <hip/hip_runtime.h>
#include <math.h>

#define BN 32
#define LL 1024
#define HH 128

typedef __attribute__((ext_vector_type(8))) short short8;
typedef __attribute__((ext_vector_type(4))) short short4v;
typedef __attribute__((ext_vector_type(4))) float f32x4;

static const size_t SZ_BF = (size_t)BN * LL * HH * 2;  // one bf16 matrix = 8 MB

__device__ __forceinline__ ushort f2bf(float x) {
  union { float f; unsigned u; } c; c.f = x;
  unsigned r = c.u + 0x7fffu + ((c.u >> 16) & 1u);
  return (ushort)(r >> 16);
}
__device__ __forceinline__ float bf2f(ushort h) {
  union { unsigned u; float f; } c; c.u = ((unsigned)h) << 16;
  return c.f;
}
__device__ __forceinline__ short8 ld8(const ushort* p) {
  return *(const short8*)p;
}

// K=16 bf16 MFMA (v_mfma_f32_16x16x16_bf16, ISA-documented on gfx950).
__device__ __forceinline__ f32x4 mfma16(short4v a, short4v b, f32x4 c) {
#if __has_builtin(__builtin_amdgcn_mfma_f32_16x16x16bf16_1k)
  return __builtin_amdgcn_mfma_f32_16x16x16bf16_1k(a, b, c, 0, 0, 0);
#elif __has_builtin(__builtin_amdgcn_mfma_f32_16x16x16_bf16)
  return __builtin_amdgcn_mfma_f32_16x16x16_bf16(a, b, c, 0, 0, 0);
#else
  f32x4 d = c;
  asm volatile("v_mfma_f32_16x16x16_bf16 %0, %1, %2, %0"
               : "+v"(d) : "v"(a), "v"(b));
  return d;
#endif
}

// ---------------------------------------------------------------------------
// k_convert: f32 -> bf16 copies of a,b plus transposed bf16 copies aT,bT.
// Fused: meanb[b][d] = sum_m b[m][d]; invmean[b][d] = sum_{m:mask_b=0} a[m][d]
// grid (16 l-tiles, 32 batches, 2 which), block 256.  (unchanged)
// ---------------------------------------------------------------------------
__global__ __launch_bounds__(256) void k_convert(
    const float* __restrict__ a, const float* __restrict__ b,
    const int* __restrict__ mask_b,
    ushort* __restrict__ abf, ushort* __restrict__ bbf,
    ushort* __restrict__ aT, ushort* __restrict__ bT,
    float* __restrict__ meanb, float* __restrict__ invmean) {
  int bb = blockIdx.y;
  int l0 = blockIdx.x * 64;
  int which = blockIdx.z;              // 0 -> a (->invmean), 1 -> b (->meanb)
  const float* src = which ? b : a;
  ushort* dst  = which ? bbf : abf;
  ushort* dstT = which ? bT : aT;
  float* dmean = which ? meanb : invmean;
  __shared__ __align__(16) ushort T[128][72];  // [d][l], padded
  __shared__ float accS[128];
  __shared__ float wgt[64];
  int t = threadIdx.x;
  if (t < 128) accS[t] = 0.f;
  if (t < 64)
    wgt[t] = which ? 1.0f : ((mask_b[bb * LL + l0 + t] == 0) ? 1.0f : 0.0f);
  int lrow = t >> 5;         // 0..7
  int dcol = (t & 31) * 4;   // 0..124
#pragma unroll
  for (int p = 0; p < 8; ++p) {
    int l = p * 8 + lrow;
    float4 v = *(const float4*)&src[((size_t)bb * LL + l0 + l) * HH + dcol];
    ushort4 u;
    u.x = f2bf(v.x); u.y = f2bf(v.y); u.z = f2bf(v.z); u.w = f2bf(v.w);
    *(ushort4*)&dst[((size_t)bb * LL + l0 + l) * HH + dcol] = u;
    T[dcol + 0][l] = u.x; T[dcol + 1][l] = u.y;
    T[dcol + 2][l] = u.z; T[dcol + 3][l] = u.w;
  }
  __syncthreads();
  int drow = t >> 3;        // 0..31
  int c8 = (t & 7) * 8;     // 0..56
#pragma unroll
  for (int q = 0; q < 4; ++q) {
    int d = q * 32 + drow;
    short8 val = *(const short8*)&T[d][c8];
    *(short8*)&dstT[((size_t)bb * HH + d) * LL + l0 + c8] = val;
    float s = 0.f;
#pragma unroll
    for (int j = 0; j < 8; ++j) s += wgt[c8 + j] * bf2f((ushort)val[j]);
    atomicAdd(&accS[d], s);
  }
  __syncthreads();
  if (t < 128) atomicAdd(&dmean[bb * HH + t], accS[t]);
}

// ---------------------------------------------------------------------------
// k_colsum: colsum[m] = sum_l exp(s[l][m]*temp + biasA[l] + biasB[m]).
// R6: exact R2-measured config (best total so far). No setprio (R4 null),
//     no XCD swizzle (R3 regression), m-tile 64, lb(256,2).
// grid (16 m-tiles, 32 batches), block 256.
// ---------------------------------------------------------------------------
__global__ __launch_bounds__(256, 2) void k_colsum(
    const ushort* __restrict__ abf, const ushort* __restrict__ bbf,
    const int* __restrict__ mask_a, const int* __restrict__ mask_b,
    const float* __restrict__ temp_p, float2* __restrict__ cc) {
  int bb = blockIdx.y;
  int m0 = blockIdx.x * 64;
  int t = threadIdx.x;
  int w = t >> 6, lane = t & 63, l16 = lane & 15, quad = lane >> 4;
  float temp = temp_p[0];
  __shared__ __align__(16) float biasA[LL];
  __shared__ float csred[4][4][16];
  for (int i = t; i < LL; i += 256)
    biasA[i] = mask_a[bb * LL + i] ? 0.0f : -10000.0f;

  short8 Bm[4][4];
  float biasB_mt[4];
#pragma unroll
  for (int mt = 0; mt < 4; ++mt) {
    int m = m0 + mt * 16 + l16;
    biasB_mt[mt] = mask_b[bb * LL + m] ? 0.0f : -10000.0f;
#pragma unroll
    for (int k = 0; k < 4; ++k)
      Bm[mt][k] = ld8(&bbf[((size_t)bb * LL + m) * HH + k * 32 + quad * 8]);
  }
  __syncthreads();

  float cs[4] = {0.f, 0.f, 0.f, 0.f};
  short8 Al0[4], Al1[4];

#define LOADAL(AlX, IT)                                                       \
  {                                                                           \
    const ushort* arow = &abf[((size_t)bb * LL + w * 256 + (IT) * 16 + l16) * HH]; \
    _Pragma("unroll") for (int k = 0; k < 4; ++k)                             \
        AlX[k] = ld8(&arow[k * 32 + quad * 8]);                               \
  }

#define CSCOMPUTE(AlX, IT)                                                    \
  {                                                                           \
    int lbase = w * 256 + (IT) * 16;                                          \
    f32x4 bA = *(const f32x4*)&biasA[lbase + quad * 4];                       \
    _Pragma("unroll") for (int mt = 0; mt < 4; ++mt) {                        \
      f32x4 sacc = {0.f, 0.f, 0.f, 0.f};                                      \
      _Pragma("unroll") for (int k = 0; k < 4; ++k)                           \
          sacc = __builtin_amdgcn_mfma_f32_16x16x32_bf16(AlX[k], Bm[mt][k],   \
                                                         sacc, 0, 0, 0);      \
      _Pragma("unroll") for (int r = 0; r < 4; ++r)                           \
          cs[mt] += __expf(sacc[r] * temp + bA[r] + biasB_mt[mt]);            \
    }                                                                         \
  }

  LOADAL(Al0, 0);
  for (int it = 0; it < 16; it += 2) {
    LOADAL(Al1, it + 1);
    CSCOMPUTE(Al0, it);
    LOADAL(Al0, (it + 2) & 15);   // last prefetch wraps to 0 (unused, in-bounds)
    CSCOMPUTE(Al1, it + 1);
  }
#undef LOADAL
#undef CSCOMPUTE

#pragma unroll
  for (int mt = 0; mt < 4; ++mt) {
    cs[mt] += __shfl_xor(cs[mt], 16);
    cs[mt] += __shfl_xor(cs[mt], 32);
  }
  if (lane < 16) {
#pragma unroll
    for (int mt = 0; mt < 4; ++mt) csred[w][mt][l16] = cs[mt];
  }
  __syncthreads();
  if (t < 64) {
    int mt = t >> 4, ml = t & 15;
    float s = csred[0][mt][ml] + csred[1][mt][ml] + csred[2][mt][ml] + csred[3][mt][ml];
    int m = m0 + t;
    float bB = mask_b[bb * LL + m] ? 0.0f : -10000.0f;
    cc[bb * LL + m] = make_float2(s > 0.f ? 1.0f / s : 0.0f, bB);
  }
}

// ---------------------------------------------------------------------------
// k_features R6: BARRIER-FREE main loop via K-split F-phase.
//   Wave w owns m-slice w*16 of each 64-wide mq tile. S output (D col=l lane,
//   row=m quad*4+r, verified C/D layout) IS the A-fragment of the K=16
//   mfma_16x16x16 (row=lane&15, k=quad*4+j) -> P stays in registers; F
//   accumulates k-partial features over ALL 128 d (acc[2][8] per matrix).
//   No LDS P-tile, no __syncthreads in the 16-iter loop. Cross-wave acc
//   reduce once at the end via LDS (wave0 store + atomicAdd).
// grid (32 l-blocks, 32 batches), block 256, lb(256,2) (~230 VGPR).
// ---------------------------------------------------------------------------
__global__ __launch_bounds__(256, 2) void k_features(
    const ushort* __restrict__ abf, const ushort* __restrict__ bbf,
    const ushort* __restrict__ aT, const ushort* __restrict__ bT,
    const int* __restrict__ mask_a, const float* __restrict__ temp_p,
    const float2* __restrict__ cc, const float* __restrict__ meanb,
    const float* __restrict__ invmean, float* __restrict__ out) {
  int bb = blockIdx.y;
  int l0 = blockIdx.x * 32;
  int t = threadIdx.x;
  int w = t >> 6, lane = t & 63, l16 = lane & 15, quad = lane >> 4;
  float temp = temp_p[0];

  __shared__ float2 ccs[LL];                        // 8 KB
  __shared__ __align__(16) short8 AfixS[512];       // 8 KB [lt][k][quad][l16]
  __shared__ __align__(16) float accRA[32][132];    // 16.9 KB (132: 16B-aligned rows)
  __shared__ __align__(16) float accRB[32][132];    // 16.9 KB
  __shared__ float rspart[4][32];
  __shared__ float rsfin[32];

  for (int i = t; i < LL; i += 256) ccs[i] = cc[bb * LL + i];

  // Afix (abf rows l0..l0+31) -> LDS, conflict-free contiguous-16B layout.
  {
    int l16p = t & 15, quadp = (t >> 4) & 3, kp = t >> 6;   // kp 0..3
#pragma unroll
    for (int lt = 0; lt < 2; ++lt) {
      short8 v = ld8(&abf[((size_t)bb * LL + l0 + lt * 16 + l16p) * HH +
                          kp * 32 + quadp * 8]);
      AfixS[((lt * 4 + kp) * 4 + quadp) * 16 + l16p] = v;
    }
  }

  float biasA_lt[2];
#pragma unroll
  for (int lt = 0; lt < 2; ++lt) {
    int l = l0 + lt * 16 + l16;
    biasA_lt[lt] = mask_a[bb * LL + l] ? 0.0f : -10000.0f;
  }

  f32x4 accA[2][8], accB[2][8];
  f32x4 zero = {0.f, 0.f, 0.f, 0.f};
#pragma unroll
  for (int lt = 0; lt < 2; ++lt)
#pragma unroll
    for (int dtt = 0; dtt < 8; ++dtt) { accA[lt][dtt] = zero; accB[lt][dtt] = zero; }
  float rs_lt[2] = {0.f, 0.f};
  __syncthreads();   // ccs + AfixS ready (the ONLY pre-loop barrier)

  for (int mq = 0; mq < LL; mq += 64) {
    int mw = mq + w * 16;              // this wave's private 16-m k-slice
    // ---- global loads (all L2-resident after first touch) ----
    short8 Am[4];
    const ushort* brow = &bbf[((size_t)bb * LL + mw + l16) * HH];
#pragma unroll
    for (int k = 0; k < 4; ++k) Am[k] = ld8(&brow[k * 32 + quad * 8]);
    short4v BbF[8], BaF[8];            // B-frags (K=16): row d, k=m quad*4..+3
#pragma unroll
    for (int dtt = 0; dtt < 8; ++dtt) {
      BbF[dtt] = *(const short4v*)&bT[((size_t)bb * HH + dtt * 16 + l16) * LL + mw + quad * 4];
      BaF[dtt] = *(const short4v*)&aT[((size_t)bb * HH + dtt * 16 + l16) * LL + mw + quad * 4];
    }
    float2 cv[4];
#pragma unroll
    for (int r = 0; r < 4; ++r) cv[r] = ccs[mw + quad * 4 + r];

    // ---- S-phase: D[m=quad*4+r][l=lt*16+l16]; P stays in registers ----
    short4v paf[2], pbf[2];
#pragma unroll
    for (int lt = 0; lt < 2; ++lt) {
      f32x4 sacc = zero;
#pragma unroll
      for (int k = 0; k < 4; ++k) {
        short8 af = AfixS[((lt * 4 + k) * 4 + quad) * 16 + l16];
        sacc = __builtin_amdgcn_mfma_f32_16x16x32_bf16(Am[k], af, sacc, 0, 0, 0);
      }
      union { ushort u[4]; short4v v; } pa_, pb_;
#pragma unroll
      for (int r = 0; r < 4; ++r) {
        float e = __expf(sacc[r] * temp + biasA_lt[lt] + cv[r].y);
        ushort pav = f2bf(e);
        pa_.u[r] = pav;
        rs_lt[lt] += bf2f(pav);        // rounded value -> cancels in fa=acc/rs
        pb_.u[r] = f2bf(e * cv[r].x);
      }
      paf[lt] = pa_.v;
      pbf[lt] = pb_.v;
    }

    // ---- F-phase: K=16 partial accumulate over all 128 d (32 indep chains)
#pragma unroll
    for (int lt = 0; lt < 2; ++lt) {
#pragma unroll
      for (int dtt = 0; dtt < 8; ++dtt) {
        accA[lt][dtt] = mfma16(paf[lt], BbF[dtt], accA[lt][dtt]);
        accB[lt][dtt] = mfma16(pbf[lt], BaF[dtt], accB[lt][dtt]);
      }
    }
  }

  // ---- rowsum cross-wave reduce + wave0 acc store ----
#pragma unroll
  for (int lt = 0; lt < 2; ++lt) {
    rs_lt[lt] += __shfl_xor(rs_lt[lt], 16);
    rs_lt[lt] += __shfl_xor(rs_lt[lt], 32);
  }
  if (lane < 16) {
#pragma unroll
    for (int lt = 0; lt < 2; ++lt) rspart[w][lt * 16 + l16] = rs_lt[lt];
  }
  if (w == 0) {
#pragma unroll
    for (int lt = 0; lt < 2; ++lt)
#pragma unroll
      for (int dtt = 0; dtt < 8; ++dtt)
#pragma unroll
        for (int r = 0; r < 4; ++r) {
          accRA[lt * 16 + quad * 4 + r][dtt * 16 + l16] = accA[lt][dtt][r];
          accRB[lt * 16 + quad * 4 + r][dtt * 16 + l16] = accB[lt][dtt][r];
        }
  }
  __syncthreads();
  if (t < 32)
    rsfin[t] = rspart[0][t] + rspart[1][t] + rspart[2][t] + rspart[3][t];
  if (w != 0) {
#pragma unroll
    for (int lt = 0; lt < 2; ++lt)
#pragma unroll
      for (int dtt = 0; dtt < 8; ++dtt)
#pragma unroll
        for (int r = 0; r < 4; ++r) {
          atomicAdd(&accRA[lt * 16 + quad * 4 + r][dtt * 16 + l16], accA[lt][dtt][r]);
          atomicAdd(&accRB[lt * 16 + quad * 4 + r][dtt * 16 + l16], accB[lt][dtt][r]);
        }
  }
  __syncthreads();

  // ---- epilogue: thread t handles row or_=t>>3, d-chunk (t&7)*16 ----
  float* outA = out;
  float* outB = out + (size_t)BN * LL * HH;
  {
    int or_ = t >> 3, oc = (t & 7) * 16;
    float rsv = rsfin[or_];
    size_t obase = ((size_t)bb * LL + l0 + or_) * HH + oc;
#pragma unroll
    for (int j = 0; j < 16; j += 4) {
      f32x4 va = *(const f32x4*)&accRA[or_][oc + j];
      f32x4 vb = *(const f32x4*)&accRB[or_][oc + j];
      float4 mbv = *(const float4*)&meanb[bb * HH + oc + j];
      float4 imv = *(const float4*)&invmean[bb * HH + oc + j];
      float4 oa, ob;
      oa.x = (rsv > 0.f) ? va[0] / rsv : mbv.x * (1.0f / 1024.0f);
      oa.y = (rsv > 0.f) ? va[1] / rsv : mbv.y * (1.0f / 1024.0f);
      oa.z = (rsv > 0.f) ? va[2] / rsv : mbv.z * (1.0f / 1024.0f);
      oa.w = (rsv > 0.f) ? va[3] / rsv : mbv.w * (1.0f / 1024.0f);
      ob.x = vb[0] + imv.x * (1.0f / 1024.0f);
      ob.y = vb[1] + imv.y * (1.0f / 1024.0f);
      ob.z = vb[2] + imv.z * (1.0f / 1024.0f);
      ob.w = vb[3] + imv.w * (1.0f / 1024.0f);
      *(float4*)&outA[obase + j] = oa;
      *(float4*)&outB[obase + j] = ob;
    }
  }
}

// ---------------------------------------------------------------------------
extern "C" void kernel_launch(void* const* d_in, const int* in_sizes, int n_in,
                              void* d_out, int out_size, void* d_ws, size_t ws_size,
                              hipStream_t stream) {
  const float* a = (const float*)d_in[0];
  const float* b = (const float*)d_in[1];
  const int* mask_a = (const int*)d_in[2];
  const int* mask_b = (const int*)d_in[3];
  const float* temp = (const float*)d_in[4];
  float* out = (float*)d_out;

  char* wsb = (char*)d_ws;
  ushort* abf = (ushort*)(wsb + 0 * SZ_BF);
  ushort* bbf = (ushort*)(wsb + 1 * SZ_BF);
  ushort* aT  = (ushort*)(wsb + 2 * SZ_BF);
  ushort* bT  = (ushort*)(wsb + 3 * SZ_BF);
  float2* cc  = (float2*)(wsb + 4 * SZ_BF);
  float* meanb   = (float*)(wsb + 4 * SZ_BF + (size_t)BN * LL * sizeof(float2));
  float* invmean = meanb + BN * HH;

  hipMemsetAsync(meanb, 0, 2 * BN * HH * sizeof(float), stream);
  k_convert<<<dim3(16, 32, 2), 256, 0, stream>>>(a, b, mask_b, abf, bbf, aT, bT,
                                                 meanb, invmean);
  k_colsum<<<dim3(16, 32), 256, 0, stream>>>(abf, bbf, mask_a, mask_b, temp, cc);
  k_features<<<dim3(32, 32), 256, 0, stream>>>(abf, bbf, aT, bT, mask_a, temp,
                                               cc, meanb, invmean, out);
  (void)in_sizes; (void)n_in; (void)out_size; (void)ws_size;
}

// Round 8
// 200.507 us; speedup vs baseline: 1.9362x; 1.9362x over previous
//
#include <hip/hip_runtime.h>
#include <math.h>

#define BN 32
#define LL 1024
#define HH 128

typedef __attribute__((ext_vector_type(8))) short short8;
typedef __attribute__((ext_vector_type(4))) float f32x4;

static const size_t SZ_BF = (size_t)BN * LL * HH * 2;  // one bf16 matrix = 8 MB

__device__ __forceinline__ ushort f2bf(float x) {
  union { float f; unsigned u; } c; c.f = x;
  unsigned r = c.u + 0x7fffu + ((c.u >> 16) & 1u);
  return (ushort)(r >> 16);
}
__device__ __forceinline__ float bf2f(ushort h) {
  union { unsigned u; float f; } c; c.u = ((unsigned)h) << 16;
  return c.f;
}
__device__ __forceinline__ short8 ld8(const ushort* p) {
  return *(const short8*)p;
}

// ---------------------------------------------------------------------------
// k_convert: f32 -> bf16 copies of a,b plus transposed bf16 copies aT,bT.
// Fused: meanb[b][d] = sum_m b[m][d]; invmean[b][d] = sum_{m:mask_b=0} a[m][d]
// grid (16 l-tiles, 32 batches, 2 which), block 256.  (unchanged)
// ---------------------------------------------------------------------------
__global__ __launch_bounds__(256) void k_convert(
    const float* __restrict__ a, const float* __restrict__ b,
    const int* __restrict__ mask_b,
    ushort* __restrict__ abf, ushort* __restrict__ bbf,
    ushort* __restrict__ aT, ushort* __restrict__ bT,
    float* __restrict__ meanb, float* __restrict__ invmean) {
  int bb = blockIdx.y;
  int l0 = blockIdx.x * 64;
  int which = blockIdx.z;              // 0 -> a (->invmean), 1 -> b (->meanb)
  const float* src = which ? b : a;
  ushort* dst  = which ? bbf : abf;
  ushort* dstT = which ? bT : aT;
  float* dmean = which ? meanb : invmean;
  __shared__ __align__(16) ushort T[128][72];  // [d][l], padded
  __shared__ float accS[128];
  __shared__ float wgt[64];
  int t = threadIdx.x;
  if (t < 128) accS[t] = 0.f;
  if (t < 64)
    wgt[t] = which ? 1.0f : ((mask_b[bb * LL + l0 + t] == 0) ? 1.0f : 0.0f);
  int lrow = t >> 5;         // 0..7
  int dcol = (t & 31) * 4;   // 0..124
#pragma unroll
  for (int p = 0; p < 8; ++p) {
    int l = p * 8 + lrow;
    float4 v = *(const float4*)&src[((size_t)bb * LL + l0 + l) * HH + dcol];
    ushort4 u;
    u.x = f2bf(v.x); u.y = f2bf(v.y); u.z = f2bf(v.z); u.w = f2bf(v.w);
    *(ushort4*)&dst[((size_t)bb * LL + l0 + l) * HH + dcol] = u;
    T[dcol + 0][l] = u.x; T[dcol + 1][l] = u.y;
    T[dcol + 2][l] = u.z; T[dcol + 3][l] = u.w;
  }
  __syncthreads();
  int drow = t >> 3;        // 0..31
  int c8 = (t & 7) * 8;     // 0..56
#pragma unroll
  for (int q = 0; q < 4; ++q) {
    int d = q * 32 + drow;
    short8 val = *(const short8*)&T[d][c8];
    *(short8*)&dstT[((size_t)bb * HH + d) * LL + l0 + c8] = val;
    float s = 0.f;
#pragma unroll
    for (int j = 0; j < 8; ++j) s += wgt[c8 + j] * bf2f((ushort)val[j]);
    atomicAdd(&accS[d], s);
  }
  __syncthreads();
  if (t < 128) atomicAdd(&dmean[bb * HH + t], accS[t]);
}

// ---------------------------------------------------------------------------
// Batch-co-locating swizzle: HW maps bid%8 -> XCD (round-robin). We assign
// bid = 8*(tile + 16*(bb>>3)) + (bb&7), a bijection on [0,512), so ALL 16
// tiles of batch bb share XCD bb&7 -> its panels live in ONE L2.
// Decode from 1-D wg:  xcd = wg&7, k = wg>>3, tile = k&15, bb = (k>>4)*8+xcd.
// ---------------------------------------------------------------------------

// ---------------------------------------------------------------------------
// k_colsum: colsum[m] = sum_l exp(s[l][m]*temp + biasA[l] + biasB[m]).
// R7: R1-measured-best body (x2 unroll, Al prefetch, vec biasA) + batch-
//     co-locating swizzle (abf panel shared in one XCD L2).
// grid 512 (1-D swizzled), block 256.
// ---------------------------------------------------------------------------
__global__ __launch_bounds__(256, 2) void k_colsum(
    const ushort* __restrict__ abf, const ushort* __restrict__ bbf,
    const int* __restrict__ mask_a, const int* __restrict__ mask_b,
    const float* __restrict__ temp_p, float2* __restrict__ cc) {
  int wg = blockIdx.x;
  int xcd = wg & 7, k_ = wg >> 3;
  int bb = (k_ >> 4) * 8 + xcd;
  int m0 = (k_ & 15) * 64;
  int t = threadIdx.x;
  int w = t >> 6, lane = t & 63, l16 = lane & 15, quad = lane >> 4;
  float temp = temp_p[0];
  __shared__ __align__(16) float biasA[LL];
  __shared__ float csred[4][4][16];
  for (int i = t; i < LL; i += 256)
    biasA[i] = mask_a[bb * LL + i] ? 0.0f : -10000.0f;

  short8 Bm[4][4];
  float biasB_mt[4];
#pragma unroll
  for (int mt = 0; mt < 4; ++mt) {
    int m = m0 + mt * 16 + l16;
    biasB_mt[mt] = mask_b[bb * LL + m] ? 0.0f : -10000.0f;
#pragma unroll
    for (int k = 0; k < 4; ++k)
      Bm[mt][k] = ld8(&bbf[((size_t)bb * LL + m) * HH + k * 32 + quad * 8]);
  }
  __syncthreads();

  float cs[4] = {0.f, 0.f, 0.f, 0.f};
  short8 Al0[4], Al1[4];

#define LOADAL(AlX, IT)                                                       \
  {                                                                           \
    const ushort* arow = &abf[((size_t)bb * LL + w * 256 + (IT) * 16 + l16) * HH]; \
    _Pragma("unroll") for (int k = 0; k < 4; ++k)                             \
        AlX[k] = ld8(&arow[k * 32 + quad * 8]);                               \
  }

#define CSCOMPUTE(AlX, IT)                                                    \
  {                                                                           \
    int lbase = w * 256 + (IT) * 16;                                          \
    f32x4 bA = *(const f32x4*)&biasA[lbase + quad * 4];                       \
    _Pragma("unroll") for (int mt = 0; mt < 4; ++mt) {                        \
      f32x4 sacc = {0.f, 0.f, 0.f, 0.f};                                      \
      _Pragma("unroll") for (int k = 0; k < 4; ++k)                           \
          sacc = __builtin_amdgcn_mfma_f32_16x16x32_bf16(AlX[k], Bm[mt][k],   \
                                                         sacc, 0, 0, 0);      \
      _Pragma("unroll") for (int r = 0; r < 4; ++r)                           \
          cs[mt] += __expf(sacc[r] * temp + bA[r] + biasB_mt[mt]);            \
    }                                                                         \
  }

  LOADAL(Al0, 0);
  for (int it = 0; it < 16; it += 2) {
    LOADAL(Al1, it + 1);
    CSCOMPUTE(Al0, it);
    LOADAL(Al0, (it + 2) & 15);   // last prefetch wraps to 0 (unused, in-bounds)
    CSCOMPUTE(Al1, it + 1);
  }
#undef LOADAL
#undef CSCOMPUTE

#pragma unroll
  for (int mt = 0; mt < 4; ++mt) {
    cs[mt] += __shfl_xor(cs[mt], 16);
    cs[mt] += __shfl_xor(cs[mt], 32);
  }
  if (lane < 16) {
#pragma unroll
    for (int mt = 0; mt < 4; ++mt) csred[w][mt][l16] = cs[mt];
  }
  __syncthreads();
  if (t < 64) {
    int mt = t >> 4, ml = t & 15;
    float s = csred[0][mt][ml] + csred[1][mt][ml] + csred[2][mt][ml] + csred[3][mt][ml];
    int m = m0 + t;
    float bB = mask_b[bb * LL + m] ? 0.0f : -10000.0f;
    cc[bb * LL + m] = make_float2(s > 0.f ? 1.0f / s : 0.0f, bB);
  }
}

// ---------------------------------------------------------------------------
// k_features: block = 64 l-rows x full m-sweep x all 128 d.
// R7: R1-measured-best body (x2 unroll, Am/cv prefetch, single-buffered
//     Bb/Ba) + batch-co-locating swizzle (bbf/aT/bT panels, 768 KB/batch,
//     resident in one XCD L2) + NON-TEMPORAL output stores (outputs bypass
//     L2 -> no panel eviction; this is the fix for R3's WRITE-doubling).
// grid 512 (1-D swizzled), block 256.
// ---------------------------------------------------------------------------
__global__ __launch_bounds__(256, 2) void k_features(
    const ushort* __restrict__ abf, const ushort* __restrict__ bbf,
    const ushort* __restrict__ aT, const ushort* __restrict__ bT,
    const int* __restrict__ mask_a, const float* __restrict__ temp_p,
    const float2* __restrict__ cc, const float* __restrict__ meanb,
    const float* __restrict__ invmean, float* __restrict__ out) {
  int wg = blockIdx.x;
  int xcd = wg & 7, k_ = wg >> 3;
  int bb = (k_ >> 4) * 8 + xcd;
  int l0 = (k_ & 15) * 64;
  int t = threadIdx.x;
  int w = t >> 6, lane = t & 63, l16 = lane & 15, quad = lane >> 4;
  float temp = temp_p[0];

  __shared__ float2 ccs[LL];                        // 8 KB
  __shared__ __align__(16) ushort Pa[2][64 * 72];   // double-buffered, 18.4 KB
  __shared__ __align__(16) ushort Pb[2][64 * 72];   // 18.4 KB
  __shared__ float rspart[4][64];
  __shared__ float rsfin[64];

  for (int i = t; i < LL; i += 256) ccs[i] = cc[bb * LL + i];

  float biasA_lt[4];
  short8 Afix[4][4];   // abf rows l0..l0+63 as B-operands (64 VGPRs)
#pragma unroll
  for (int lt = 0; lt < 4; ++lt) {
    int l = l0 + lt * 16 + l16;
    biasA_lt[lt] = mask_a[bb * LL + l] ? 0.0f : -10000.0f;
#pragma unroll
    for (int k = 0; k < 4; ++k)
      Afix[lt][k] = ld8(&abf[((size_t)bb * LL + l) * HH + k * 32 + quad * 8]);
  }

  f32x4 accA[4][2], accB[4][2];
  f32x4 zero = {0.f, 0.f, 0.f, 0.f};
#pragma unroll
  for (int lt = 0; lt < 4; ++lt)
#pragma unroll
    for (int dt = 0; dt < 2; ++dt) { accA[lt][dt] = zero; accB[lt][dt] = zero; }
  float rs_lt[4] = {0.f, 0.f, 0.f, 0.f};
  __syncthreads();   // ccs ready

  short8 Am0[4], Am1[4];
  float2 cv0[4], cv1[4];
  short8 Bb[2][2], Ba[2][2];

#define LOADAM(AmX, cvX, M0)                                                  \
  {                                                                           \
    const ushort* brow = &bbf[((size_t)bb * LL + (M0) + w * 16 + l16) * HH];  \
    _Pragma("unroll") for (int k = 0; k < 4; ++k)                             \
        AmX[k] = ld8(&brow[k * 32 + quad * 8]);                               \
    _Pragma("unroll") for (int r = 0; r < 4; ++r)                             \
        cvX[r] = ccs[(M0) + w * 16 + quad * 4 + r];                           \
  }

#define LOADBT(M0)                                                            \
  {                                                                           \
    _Pragma("unroll") for (int dt = 0; dt < 2; ++dt) {                        \
      const ushort* btrow =                                                   \
          &bT[((size_t)bb * HH + w * 32 + dt * 16 + l16) * LL + (M0)];        \
      const ushort* atrow =                                                   \
          &aT[((size_t)bb * HH + w * 32 + dt * 16 + l16) * LL + (M0)];        \
      _Pragma("unroll") for (int ks = 0; ks < 2; ++ks) {                      \
        Bb[dt][ks] = ld8(&btrow[ks * 32 + quad * 8]);                         \
        Ba[dt][ks] = ld8(&atrow[ks * 32 + quad * 8]);                         \
      }                                                                       \
    }                                                                         \
  }

#define SPHASE(AmX, cvX)                                                      \
  {                                                                           \
    ushort* pa = &Pa[buf][0];                                                 \
    ushort* pb = &Pb[buf][0];                                                 \
    _Pragma("unroll") for (int lt = 0; lt < 4; ++lt) {                        \
      f32x4 sacc = zero;                                                      \
      _Pragma("unroll") for (int k = 0; k < 4; ++k)                           \
          sacc = __builtin_amdgcn_mfma_f32_16x16x32_bf16(AmX[k], Afix[lt][k], \
                                                         sacc, 0, 0, 0);      \
      ushort pav[4], pbv[4];                                                  \
      _Pragma("unroll") for (int r = 0; r < 4; ++r) {                         \
        float e = __expf(sacc[r] * temp + biasA_lt[lt] + cvX[r].y);           \
        pav[r] = f2bf(e);                                                     \
        rs_lt[lt] += bf2f(pav[r]);                                            \
        pbv[r] = f2bf(e * cvX[r].x);                                          \
      }                                                                       \
      uint2 ka, kb;                                                           \
      ka.x = (uint)pav[0] | ((uint)pav[1] << 16);                             \
      ka.y = (uint)pav[2] | ((uint)pav[3] << 16);                             \
      kb.x = (uint)pbv[0] | ((uint)pbv[1] << 16);                             \
      kb.y = (uint)pbv[2] | ((uint)pbv[3] << 16);                             \
      int pidx = (lt * 16 + l16) * 72 + w * 16 + quad * 4;                    \
      *(uint2*)&pa[pidx] = ka;                                                \
      *(uint2*)&pb[pidx] = kb;                                                \
    }                                                                         \
  }

#define FPHASE()                                                              \
  {                                                                           \
    const ushort* pa = &Pa[buf][0];                                           \
    const ushort* pb = &Pb[buf][0];                                           \
    _Pragma("unroll") for (int lt = 0; lt < 4; ++lt) {                        \
      _Pragma("unroll") for (int ks = 0; ks < 2; ++ks) {                      \
        int ridx = (lt * 16 + l16) * 72 + ks * 32 + quad * 8;                 \
        short8 PaF = *(const short8*)&pa[ridx];                               \
        short8 PbF = *(const short8*)&pb[ridx];                               \
        _Pragma("unroll") for (int dt = 0; dt < 2; ++dt) {                    \
          accA[lt][dt] = __builtin_amdgcn_mfma_f32_16x16x32_bf16(             \
              PaF, Bb[dt][ks], accA[lt][dt], 0, 0, 0);                        \
          accB[lt][dt] = __builtin_amdgcn_mfma_f32_16x16x32_bf16(             \
              PbF, Ba[dt][ks], accB[lt][dt], 0, 0, 0);                        \
        }                                                                     \
      }                                                                       \
    }                                                                         \
  }

  LOADAM(Am0, cv0, 0);
  int buf = 0;
  for (int m0 = 0; m0 < LL; m0 += 128) {
    LOADBT(m0);                                 // F-operands, hidden by S-phase
    LOADAM(Am1, cv1, m0 + 64);                  // next tile S-operands (T14)
    SPHASE(Am0, cv0);
    __syncthreads();   // P[buf] complete (prev buf still readable -> 1 barrier)
    FPHASE();
    buf ^= 1;
    LOADBT(m0 + 64);
    LOADAM(Am0, cv0, (m0 + 128) & (LL - 1));    // last wraps to 0 (unused)
    SPHASE(Am1, cv1);
    __syncthreads();
    FPHASE();
    buf ^= 1;
  }
#undef LOADAM
#undef LOADBT
#undef SPHASE
#undef FPHASE

  // ---- rowsum cross-wave reduce ----
#pragma unroll
  for (int lt = 0; lt < 4; ++lt) {
    rs_lt[lt] += __shfl_xor(rs_lt[lt], 16);
    rs_lt[lt] += __shfl_xor(rs_lt[lt], 32);
  }
  if (lane < 16) {
#pragma unroll
    for (int lt = 0; lt < 4; ++lt) rspart[w][lt * 16 + l16] = rs_lt[lt];
  }
  __syncthreads();
  if (t < 64)
    rsfin[t] = rspart[0][t] + rspart[1][t] + rspart[2][t] + rspart[3][t];
  __syncthreads();

  // ---- epilogue: NON-TEMPORAL stores (bypass L2, keep panels resident) ----
  float* outA = out;
  float* outB = out + (size_t)BN * LL * HH;
#pragma unroll
  for (int dt = 0; dt < 2; ++dt) {
    int d = w * 32 + dt * 16 + l16;
    float mb = meanb[bb * HH + d] * (1.0f / 1024.0f);
    float im = invmean[bb * HH + d] * (1.0f / 1024.0f);
#pragma unroll
    for (int lt = 0; lt < 4; ++lt) {
#pragma unroll
      for (int r = 0; r < 4; ++r) {
        int l = lt * 16 + quad * 4 + r;
        float rsv = rsfin[l];
        float fa = (rsv > 0.f) ? accA[lt][dt][r] / rsv : mb;
        float fb = accB[lt][dt][r] + im;
        __builtin_nontemporal_store(fa, &outA[((size_t)bb * LL + l0 + l) * HH + d]);
        __builtin_nontemporal_store(fb, &outB[((size_t)bb * LL + l0 + l) * HH + d]);
      }
    }
  }
}

// ---------------------------------------------------------------------------
extern "C" void kernel_launch(void* const* d_in, const int* in_sizes, int n_in,
                              void* d_out, int out_size, void* d_ws, size_t ws_size,
                              hipStream_t stream) {
  const float* a = (const float*)d_in[0];
  const float* b = (const float*)d_in[1];
  const int* mask_a = (const int*)d_in[2];
  const int* mask_b = (const int*)d_in[3];
  const float* temp = (const float*)d_in[4];
  float* out = (float*)d_out;

  char* wsb = (char*)d_ws;
  ushort* abf = (ushort*)(wsb + 0 * SZ_BF);
  ushort* bbf = (ushort*)(wsb + 1 * SZ_BF);
  ushort* aT  = (ushort*)(wsb + 2 * SZ_BF);
  ushort* bT  = (ushort*)(wsb + 3 * SZ_BF);
  float2* cc  = (float2*)(wsb + 4 * SZ_BF);
  float* meanb   = (float*)(wsb + 4 * SZ_BF + (size_t)BN * LL * sizeof(float2));
  float* invmean = meanb + BN * HH;

  hipMemsetAsync(meanb, 0, 2 * BN * HH * sizeof(float), stream);
  k_convert<<<dim3(16, 32, 2), 256, 0, stream>>>(a, b, mask_b, abf, bbf, aT, bT,
                                                 meanb, invmean);
  k_colsum<<<dim3(512), 256, 0, stream>>>(abf, bbf, mask_a, mask_b, temp, cc);
  k_features<<<dim3(512), 256, 0, stream>>>(abf, bbf, aT, bT, mask_a, temp,
                                            cc, meanb, invmean, out);
  (void)in_sizes; (void)n_in; (void)out_size; (void)ws_size;
}